// Round 16
// baseline (170.785 us; speedup 1.0000x reference)
//
#include <hip/hip_runtime.h>
#include <hip/hip_bf16.h>

#define N_SRC 50000
#define N_DST 10000
#define KNBR  32
#define IN_F  256
#define OUT_F 128
#define LDIM  10
#define ATTN_OUT 1024
#define NB2_BIG  1563   // ceil(50000/32)
#define NB2_SELF 313    // ceil(10000/32)
#define NB2_TOT  1876   // 32-row blocks, 128 threads (2 waves). MUST stay <= 2048
                        // (= 256 CU x 8 blocks/CU at lb(128,4)) for spin-safety.
#define NPREP    384    // prep-task blocks (128 w_comb | 128 Bn | 128 Bs)

using f32x4 = __attribute__((ext_vector_type(4))) float;
using s16x8 = __attribute__((ext_vector_type(8))) short;

// Output layout (floats): rst (N_DST*128) | cent_l (N_DST*10) | labels_ori[:N_DST] (N_DST*10)
#define OUT_CENT (N_DST*OUT_F)
#define OUT_LORI (N_DST*OUT_F + N_DST*LDIM)

// Workspace float offsets
#define WS_WCOMB 0                                   // 128 floats
#define WS_BN    128                                 // 32768 ushort
#define WS_BS    (128 + 16384)                       // 32768 ushort
#define WS_HSRC  (128 + 32768)                       // N_SRC*128 ushort
#define WS_SELF0 (WS_HSRC + (N_SRC*OUT_F/2))         // N_DST*128 floats
#define WS_SCORE (WS_SELF0 + N_DST*OUT_F)            // N_SRC floats
#define WS_CNT   (WS_SCORE + N_SRC + 64)             // 1 uint (prep barrier)

__device__ __forceinline__ ushort f2bf(float x) {
  __hip_bfloat16 h = __float2bfloat16(x);
  return *reinterpret_cast<ushort*>(&h);
}

__device__ __forceinline__ void unpack8(uint4 hv, float* o) {
  o[0] = __uint_as_float(hv.x << 16);
  o[1] = __uint_as_float(hv.x & 0xffff0000u);
  o[2] = __uint_as_float(hv.y << 16);
  o[3] = __uint_as_float(hv.y & 0xffff0000u);
  o[4] = __uint_as_float(hv.z << 16);
  o[5] = __uint_as_float(hv.z & 0xffff0000u);
  o[6] = __uint_as_float(hv.w << 16);
  o[7] = __uint_as_float(hv.w & 0xffff0000u);
}

// ---------------------------------------------------------------------------
// Merged prep + GEMM. Per block:
//   (a) blocks 0..383: prep task (w_comb / Bn / Bs), release-add counter
//   (b) ALL blocks: issue A row loads + cvt (prep-independent -> hides (a))
//   (c) spin until counter==384, acquire fence  [pattern proven correct in R13]
//   (d) R15-exact MFMA + epilogue (+ per-row score for neigh tiles)
// ---------------------------------------------------------------------------
__global__ __launch_bounds__(128, 4) void prep_gemm(
    const float* __restrict__ A,
    const float* __restrict__ W_attn, const float* __restrict__ fW,
    const float* __restrict__ W_neigh, const float* __restrict__ W_self,
    const float* __restrict__ bias_n, const float* __restrict__ bias_s,
    float* __restrict__ w_comb, ushort* __restrict__ Bn, ushort* __restrict__ Bs,
    ushort* __restrict__ hsrc, float* __restrict__ self0, float* __restrict__ score_f,
    uint* __restrict__ cnt) {
  const int b = blockIdx.x;
  const int t = threadIdx.x;
  const int wv = t >> 6, ln = t & 63;
  const int dg = ln & 15, kg = ln >> 4;

  const bool neigh = b < NB2_BIG;
  const int M = neigh ? N_SRC : N_DST;
  const int m0 = (neigh ? b : b - NB2_BIG) * 32;

  // ---- (a) prep task ----
  if (b < NPREP) {
    if (b < 128) {
      __shared__ float red[128];
      float s = 0.f;
#pragma unroll
      for (int i = 0; i < 8; ++i) {
        int o = t + i * 128;
        s += W_attn[(size_t)b * ATTN_OUT + o] * fW[o];
      }
      red[t] = s;
      __syncthreads();
      for (int st = 64; st > 0; st >>= 1) {
        if (t < st) red[t] += red[t + st];
        __syncthreads();
      }
      if (t == 0) w_comb[b] = red[0];
    } else if (b < 256) {
      int k = 2 * (b - 128) + (t >> 6);
      int n0 = (t & 63) * 2;
      ushort* dst = (b < 256) ? Bn : Bs;
#pragma unroll
      for (int i = 0; i < 2; ++i) {
        int n = n0 + i;
        Bn[(k >> 3) * 1024 + n * 8 + (k & 7)] = f2bf(W_neigh[(size_t)k * OUT_F + n]);
      }
    } else {
      int k = 2 * (b - 256) + (t >> 6);
      int n0 = (t & 63) * 2;
#pragma unroll
      for (int i = 0; i < 2; ++i) {
        int n = n0 + i;
        Bs[(k >> 3) * 1024 + n * 8 + (k & 7)] = f2bf(W_self[(size_t)k * OUT_F + n]);
      }
    }
    __syncthreads();   // drains this block's stores (vmcnt(0) before s_barrier)
    if (t == 0) {
      __threadfence();
      __hip_atomic_fetch_add(cnt, 1u, __ATOMIC_RELEASE, __HIP_MEMORY_SCOPE_AGENT);
    }
  }

  // ---- (b) A loads + cvt (independent of prep) ----
  int r = m0 + wv * 16 + dg;
  r = r < M ? r : M - 1;                    // branchless clamp: loads always valid
  const float* arow = &A[(size_t)r * IN_F];

  s16x8 afr[8];
#pragma unroll
  for (int half = 0; half < 2; ++half) {
    f32x4 araw[8];
#pragma unroll
    for (int k0 = 0; k0 < 4; ++k0) {
      const f32x4* ap = (const f32x4*)&arow[(half * 4 + k0) * 32 + kg * 8];
      araw[2 * k0]     = ap[0];
      araw[2 * k0 + 1] = ap[1];
    }
#pragma unroll
    for (int k0 = 0; k0 < 4; ++k0) {
      s16x8 f;
      f[0] = (short)f2bf(araw[2*k0][0]); f[1] = (short)f2bf(araw[2*k0][1]);
      f[2] = (short)f2bf(araw[2*k0][2]); f[3] = (short)f2bf(araw[2*k0][3]);
      f[4] = (short)f2bf(araw[2*k0+1][0]); f[5] = (short)f2bf(araw[2*k0+1][1]);
      f[6] = (short)f2bf(araw[2*k0+1][2]); f[7] = (short)f2bf(araw[2*k0+1][3]);
      afr[half * 4 + k0] = f;
    }
  }

  // ---- (c) wait for prep producers ----
  __syncthreads();
  if (t == 0) {
    while (__hip_atomic_load(cnt, __ATOMIC_ACQUIRE, __HIP_MEMORY_SCOPE_AGENT) < (uint)NPREP) {
      __builtin_amdgcn_s_sleep(2);
    }
    __threadfence();
  }
  __syncthreads();

  // ---- (d) MFMA + epilogue (R15-exact) ----
  const ushort* Bp = neigh ? Bn : Bs;
  const float* bias = neigh ? bias_n : bias_s;

  f32x4 acc[8];
#pragma unroll
  for (int ct = 0; ct < 8; ++ct) acc[ct] = (f32x4){0.f, 0.f, 0.f, 0.f};
#pragma unroll
  for (int k0 = 0; k0 < 8; ++k0) {
    const ushort* bb = Bp + (k0 * 4 + kg) * 1024 + dg * 8;
#pragma unroll
    for (int ct = 0; ct < 8; ++ct) {
      s16x8 bfr = *reinterpret_cast<const s16x8*>(bb + ct * 128);
      acc[ct] = __builtin_amdgcn_mfma_f32_16x16x32_bf16(afr[k0], bfr, acc[ct], 0, 0, 0);
    }
  }

  // Epilogue. D layout: col = ct*16+dg, row = m0+wv*16+kg*4+e (HW-verified m89).
  float sc[4] = {0.f, 0.f, 0.f, 0.f};
#pragma unroll
  for (int ct = 0; ct < 8; ++ct) {
    int col = ct * 16 + dg;
    float bb = bias[col];
    float wc = neigh ? w_comb[col] : 0.f;
#pragma unroll
    for (int e = 0; e < 4; ++e) {
      int rr = m0 + wv * 16 + kg * 4 + e;
      float v = acc[ct][e] + bb;
      if (neigh) {
        sc[e] = fmaf(fmaxf(v, 0.1f * v), wc, sc[e]);
        if (rr < M) hsrc[(size_t)rr * OUT_F + col] = f2bf(v);
      } else {
        if (rr < M) self0[(size_t)rr * OUT_F + col] = v;
      }
    }
  }
  if (neigh) {
#pragma unroll
    for (int s = 1; s < 16; s <<= 1) {
#pragma unroll
      for (int e = 0; e < 4; ++e) sc[e] += __shfl_xor(sc[e], s);
    }
    if (dg == 0) {
#pragma unroll
      for (int e = 0; e < 4; ++e) {
        int rr = m0 + wv * 16 + kg * 4 + e;
        if (rr < M) score_f[rr] = sc[e];
      }
    }
  }
}

// ---------------------------------------------------------------------------
// attn (R14 exact, lb(256,6) — measured best)
// ---------------------------------------------------------------------------
__global__ __launch_bounds__(256, 6) void attn_kernel(
    const float* __restrict__ labels, const float* __restrict__ labels_ori,
    const float* __restrict__ label_rela, const int* __restrict__ nbr_idx,
    const ushort* __restrict__ hsrc, const float* __restrict__ self0,
    const float* __restrict__ score_f, const float* __restrict__ eps_p,
    const float* __restrict__ out_bias, float* __restrict__ out) {
  const int t = threadIdx.x;
  const int wv = t >> 6, ln = t & 63;
  const int n = blockIdx.x * 4 + wv;
  const int dg = ln & 15, kg = ln >> 4;

  const float eps = eps_p[0];
  const float om = 1.f - eps;

  float va = 0.f;
  if (dg < LDIM) {
#pragma unroll
    for (int b = 0; b < LDIM; ++b)
      va += label_rela[dg * LDIM + b] * labels[(size_t)n * LDIM + b];
    va *= eps;
  }

  const int* irow = nbr_idx + (size_t)n * KNBR;
  int ids[8];
  uint4 hv[8];
#pragma unroll
  for (int j = 0; j < 8; ++j) {
    ids[j] = irow[kg * 8 + j];
    hv[j] = *(const uint4*)(hsrc + (size_t)ids[j] * OUT_F + dg * 8);
  }
  float m[8];
#pragma unroll
  for (int j = 0; j < 8; ++j) {
    float sp = 0.f;
    if (dg == 0) sp = om * score_f[ids[j]];
    if (dg < LDIM) sp = fmaf(labels[(size_t)ids[j] * LDIM + dg], va, sp);
    m[j] = sp;
  }
#pragma unroll
  for (int s = 1; s < 16; s <<= 1) {
#pragma unroll
    for (int j = 0; j < 8; ++j) m[j] += __shfl_xor(m[j], s);
  }
  float mx = m[0];
#pragma unroll
  for (int j = 1; j < 8; ++j) mx = fmaxf(mx, m[j]);
  mx = fmaxf(mx, __shfl_xor(mx, 16));
  mx = fmaxf(mx, __shfl_xor(mx, 32));
  float ssum = 0.f;
#pragma unroll
  for (int j = 0; j < 8; ++j) {
    m[j] = __expf(m[j] - mx);
    ssum += m[j];
  }
  ssum += __shfl_xor(ssum, 16);
  ssum += __shfl_xor(ssum, 32);
  const float scale = 1.f / (ssum * (float)KNBR);
  float pn[8];
#pragma unroll
  for (int e = 0; e < 8; ++e) pn[e] = 0.f;
#pragma unroll
  for (int j = 0; j < 8; ++j) {
    float a = m[j];
    float hfj[8];
    unpack8(hv[j], hfj);
#pragma unroll
    for (int e = 0; e < 8; ++e) pn[e] = fmaf(a, hfj[e], pn[e]);
  }
#pragma unroll
  for (int e = 0; e < 8; ++e) {
    pn[e] += __shfl_xor(pn[e], 16);
    pn[e] += __shfl_xor(pn[e], 32);
  }
  if (kg == 0) {
    const float* srow = self0 + (size_t)n * OUT_F + dg * 8;
    float* orow = out + (size_t)n * OUT_F + dg * 8;
    f32x4 o0, o1;
#pragma unroll
    for (int e = 0; e < 4; ++e)
      o0[e] = (srow[e] + pn[e] * scale) * 0.5f + out_bias[dg * 8 + e];
#pragma unroll
    for (int e = 0; e < 4; ++e)
      o1[e] = (srow[4 + e] + pn[4 + e] * scale) * 0.5f + out_bias[dg * 8 + 4 + e];
    *(f32x4*)orow = o0;
    *(f32x4*)(orow + 4) = o1;
  }
  if (kg == 1 && dg < LDIM)
    out[OUT_CENT + (size_t)n * LDIM + dg] = labels[(size_t)n * LDIM + dg];
  if (kg == 2 && dg < LDIM)
    out[OUT_LORI + (size_t)n * LDIM + dg] = labels_ori[(size_t)n * LDIM + dg];
}

// ---------------------------------------------------------------------------
extern "C" void kernel_launch(void* const* d_in, const int* in_sizes, int n_in,
                              void* d_out, int out_size, void* d_ws, size_t ws_size,
                              hipStream_t stream) {
  const float* feat       = (const float*)d_in[0];
  const float* labels     = (const float*)d_in[1];
  const float* labels_ori = (const float*)d_in[2];
  const float* label_rela = (const float*)d_in[3];
  const float* W_neigh    = (const float*)d_in[4];
  const float* b_neigh    = (const float*)d_in[5];
  const float* W_self     = (const float*)d_in[6];
  const float* b_self     = (const float*)d_in[7];
  const float* W_attn     = (const float*)d_in[8];
  // d_in[9] = b_attn (constant under softmax -> unused)
  const float* fW         = (const float*)d_in[10];
  const float* eps        = (const float*)d_in[11];
  const float* out_bias   = (const float*)d_in[12];
  const int*   nbr_idx    = (const int*)d_in[13];

  float* wsf = (float*)d_ws;
  float* out = (float*)d_out;

  float*  w_comb  = wsf + WS_WCOMB;
  ushort* Bn      = (ushort*)(wsf + WS_BN);
  ushort* Bsf     = (ushort*)(wsf + WS_BS);
  ushort* h_src   = (ushort*)(wsf + WS_HSRC);
  float*  self0   = wsf + WS_SELF0;
  float*  score_f = wsf + WS_SCORE;
  uint*   cnt     = (uint*)(wsf + WS_CNT);

  hipMemsetAsync((void*)cnt, 0, sizeof(uint), stream);
  prep_gemm<<<NB2_TOT, 128, 0, stream>>>(feat, W_attn, fW, W_neigh, W_self,
                                         b_neigh, b_self, w_comb, Bn, Bsf,
                                         h_src, self0, score_f, cnt);
  attn_kernel<<<(N_DST / 4), 256, 0, stream>>>(labels, labels_ori, label_rela, nbr_idx,
                                               h_src, self0, score_f, eps, out_bias, out);
}

// Round 17
// 58.372 us; speedup vs baseline: 2.9258x; 2.9258x over previous
//
#include <hip/hip_runtime.h>
#include <hip/hip_bf16.h>

#define N_SRC 50000
#define N_DST 10000
#define KNBR  32
#define IN_F  256
#define OUT_F 128
#define LDIM  10
#define ATTN_OUT 1024
#define NB2_BIG  1563   // ceil(50000/32)
#define NB2_SELF 313    // ceil(10000/32)
#define NB2_TOT  1876   // 32-row blocks, 128 threads (2 waves), R5-identical per-wave body

using f32x4 = __attribute__((ext_vector_type(4))) float;
using s16x8 = __attribute__((ext_vector_type(8))) short;

// Output layout (floats): rst (N_DST*128) | cent_l (N_DST*10) | labels_ori[:N_DST] (N_DST*10)
#define OUT_CENT (N_DST*OUT_F)
#define OUT_LORI (N_DST*OUT_F + N_DST*LDIM)

// Workspace float offsets
#define WS_WCOMB 0                                   // 128 floats
#define WS_BN    128                                 // 32768 ushort
#define WS_BS    (128 + 16384)                       // 32768 ushort
#define WS_HSRC  (128 + 32768)                       // N_SRC*128 ushort
#define WS_SELF0 (WS_HSRC + (N_SRC*OUT_F/2))         // N_DST*128 floats
#define WS_SCORE (WS_SELF0 + N_DST*OUT_F)            // N_SRC floats

__device__ __forceinline__ ushort f2bf(float x) {
  __hip_bfloat16 h = __float2bfloat16(x);
  return *reinterpret_cast<ushort*>(&h);
}

__device__ __forceinline__ void unpack8(uint4 hv, float* o) {
  o[0] = __uint_as_float(hv.x << 16);
  o[1] = __uint_as_float(hv.x & 0xffff0000u);
  o[2] = __uint_as_float(hv.y << 16);
  o[3] = __uint_as_float(hv.y & 0xffff0000u);
  o[4] = __uint_as_float(hv.z << 16);
  o[5] = __uint_as_float(hv.z & 0xffff0000u);
  o[6] = __uint_as_float(hv.w << 16);
  o[7] = __uint_as_float(hv.w & 0xffff0000u);
}

// ---------------------------------------------------------------------------
// prep: blocks 0..127 w_comb | 128..255 W_neigh->bf16 subtile | 256..383 W_self
// ---------------------------------------------------------------------------
__global__ __launch_bounds__(256) void prep_kernel(
    const float* __restrict__ W_attn, const float* __restrict__ fW,
    const float* __restrict__ W_neigh, const float* __restrict__ W_self,
    float* __restrict__ w_comb, ushort* __restrict__ Bn, ushort* __restrict__ Bs) {
  const int b = blockIdx.x;
  const int t = threadIdx.x;
  if (b < 128) {
    __shared__ float red[256];
    float s = 0.f;
#pragma unroll
    for (int i = 0; i < 4; ++i) {
      int o = t + i * 256;
      s += W_attn[(size_t)b * ATTN_OUT + o] * fW[o];
    }
    red[t] = s;
    __syncthreads();
    for (int st = 128; st > 0; st >>= 1) {
      if (t < st) red[t] += red[t + st];
      __syncthreads();
    }
    if (t == 0) w_comb[b] = red[0];
  } else if (b < 256) {
    int k = 2 * (b - 128) + (t >> 7);
    int n = t & 127;
    Bn[(k >> 3) * 1024 + n * 8 + (k & 7)] = f2bf(W_neigh[(size_t)k * OUT_F + n]);
  } else {
    int k = 2 * (b - 256) + (t >> 7);
    int n = t & 127;
    Bs[(k >> 3) * 1024 + n * 8 + (k & 7)] = f2bf(W_self[(size_t)k * OUT_F + n]);
  }
}

// ---------------------------------------------------------------------------
// GEMM: R5-exact per-wave body (16 rows/wave, two 8x16B A batches, B-frags
// streamed from the L2/L3-resident pre-subtiled table), 32-row/128-thread
// blocks (R15 granularity). Neigh path emits per-row
// score_f = dot(leaky(h_r), w_comb) in the epilogue.
// ---------------------------------------------------------------------------
template<bool OUT_BF16>
__device__ __forceinline__ void gemm_body(
    const float* __restrict__ A, const ushort* __restrict__ Bp,
    const float* __restrict__ bias, const float* __restrict__ w_comb,
    void* __restrict__ C, float* __restrict__ score_f, int M, int m0) {
  const int t = threadIdx.x;
  const int wv = t >> 6, ln = t & 63;
  const int dg = ln & 15, kg = ln >> 4;
  int r = m0 + wv * 16 + dg;
  r = r < M ? r : M - 1;                    // branchless clamp: loads always valid
  const float* arow = &A[(size_t)r * IN_F];

  s16x8 afr[8];
#pragma unroll
  for (int half = 0; half < 2; ++half) {
    f32x4 araw[8];
#pragma unroll
    for (int k0 = 0; k0 < 4; ++k0) {
      const f32x4* ap = (const f32x4*)&arow[(half * 4 + k0) * 32 + kg * 8];
      araw[2 * k0]     = ap[0];
      araw[2 * k0 + 1] = ap[1];
    }
#pragma unroll
    for (int k0 = 0; k0 < 4; ++k0) {
      s16x8 f;
      f[0] = (short)f2bf(araw[2*k0][0]); f[1] = (short)f2bf(araw[2*k0][1]);
      f[2] = (short)f2bf(araw[2*k0][2]); f[3] = (short)f2bf(araw[2*k0][3]);
      f[4] = (short)f2bf(araw[2*k0+1][0]); f[5] = (short)f2bf(araw[2*k0+1][1]);
      f[6] = (short)f2bf(araw[2*k0+1][2]); f[7] = (short)f2bf(araw[2*k0+1][3]);
      afr[half * 4 + k0] = f;
    }
  }

  f32x4 acc[8];
#pragma unroll
  for (int ct = 0; ct < 8; ++ct) acc[ct] = (f32x4){0.f, 0.f, 0.f, 0.f};
#pragma unroll
  for (int k0 = 0; k0 < 8; ++k0) {
    const ushort* bb = Bp + (k0 * 4 + kg) * 1024 + dg * 8;
#pragma unroll
    for (int ct = 0; ct < 8; ++ct) {
      s16x8 bfr = *reinterpret_cast<const s16x8*>(bb + ct * 128);
      acc[ct] = __builtin_amdgcn_mfma_f32_16x16x32_bf16(afr[k0], bfr, acc[ct], 0, 0, 0);
    }
  }

  // Epilogue. D layout: col = ct*16+dg, row = m0+wv*16+kg*4+e (HW-verified m89).
  float sc[4] = {0.f, 0.f, 0.f, 0.f};
#pragma unroll
  for (int ct = 0; ct < 8; ++ct) {
    int col = ct * 16 + dg;
    float bb = bias[col];
    float wc = OUT_BF16 ? w_comb[col] : 0.f;
#pragma unroll
    for (int e = 0; e < 4; ++e) {
      int rr = m0 + wv * 16 + kg * 4 + e;
      float v = acc[ct][e] + bb;
      if (OUT_BF16) {
        sc[e] = fmaf(fmaxf(v, 0.1f * v), wc, sc[e]);
        if (rr < M) ((ushort*)C)[(size_t)rr * OUT_F + col] = f2bf(v);
      } else {
        if (rr < M) ((float*)C)[(size_t)rr * OUT_F + col] = v;
      }
    }
  }
  if (OUT_BF16) {
#pragma unroll
    for (int s = 1; s < 16; s <<= 1) {
#pragma unroll
      for (int e = 0; e < 4; ++e) sc[e] += __shfl_xor(sc[e], s);
    }
    if (dg == 0) {
#pragma unroll
      for (int e = 0; e < 4; ++e) {
        int rr = m0 + wv * 16 + kg * 4 + e;
        if (rr < M) score_f[rr] = sc[e];
      }
    }
  }
}

__global__ __launch_bounds__(128, 4) void fused_gemm(
    const float* __restrict__ A,
    const ushort* __restrict__ Bn, const ushort* __restrict__ Bs,
    const float* __restrict__ bias_n, const float* __restrict__ bias_s,
    const float* __restrict__ w_comb,
    ushort* __restrict__ hsrc, float* __restrict__ self0, float* __restrict__ score_f) {
  if (blockIdx.x < NB2_BIG)
    gemm_body<true>(A, Bn, bias_n, w_comb, (void*)hsrc, score_f, N_SRC, blockIdx.x * 32);
  else
    gemm_body<false>(A, Bs, bias_s, w_comb, (void*)self0, score_f, N_DST,
                     (blockIdx.x - NB2_BIG) * 32);
}

// ---------------------------------------------------------------------------
// attn (R14 exact, lb(256,6) — measured best): one wave per dst node;
// score gathered from score_f; packed h gathers feed only PV.
// ---------------------------------------------------------------------------
__global__ __launch_bounds__(256, 6) void attn_kernel(
    const float* __restrict__ labels, const float* __restrict__ labels_ori,
    const float* __restrict__ label_rela, const int* __restrict__ nbr_idx,
    const ushort* __restrict__ hsrc, const float* __restrict__ self0,
    const float* __restrict__ score_f, const float* __restrict__ eps_p,
    const float* __restrict__ out_bias, float* __restrict__ out) {
  const int t = threadIdx.x;
  const int wv = t >> 6, ln = t & 63;
  const int n = blockIdx.x * 4 + wv;
  const int dg = ln & 15, kg = ln >> 4;

  const float eps = eps_p[0];
  const float om = 1.f - eps;

  float va = 0.f;
  if (dg < LDIM) {
#pragma unroll
    for (int b = 0; b < LDIM; ++b)
      va += label_rela[dg * LDIM + b] * labels[(size_t)n * LDIM + b];
    va *= eps;
  }

  const int* irow = nbr_idx + (size_t)n * KNBR;
  int ids[8];
  uint4 hv[8];
#pragma unroll
  for (int j = 0; j < 8; ++j) {
    ids[j] = irow[kg * 8 + j];
    hv[j] = *(const uint4*)(hsrc + (size_t)ids[j] * OUT_F + dg * 8);
  }
  float m[8];
#pragma unroll
  for (int j = 0; j < 8; ++j) {
    float sp = 0.f;
    if (dg == 0) sp = om * score_f[ids[j]];
    if (dg < LDIM) sp = fmaf(labels[(size_t)ids[j] * LDIM + dg], va, sp);
    m[j] = sp;
  }
#pragma unroll
  for (int s = 1; s < 16; s <<= 1) {
#pragma unroll
    for (int j = 0; j < 8; ++j) m[j] += __shfl_xor(m[j], s);
  }
  float mx = m[0];
#pragma unroll
  for (int j = 1; j < 8; ++j) mx = fmaxf(mx, m[j]);
  mx = fmaxf(mx, __shfl_xor(mx, 16));
  mx = fmaxf(mx, __shfl_xor(mx, 32));
  float ssum = 0.f;
#pragma unroll
  for (int j = 0; j < 8; ++j) {
    m[j] = __expf(m[j] - mx);
    ssum += m[j];
  }
  ssum += __shfl_xor(ssum, 16);
  ssum += __shfl_xor(ssum, 32);
  const float scale = 1.f / (ssum * (float)KNBR);
  float pn[8];
#pragma unroll
  for (int e = 0; e < 8; ++e) pn[e] = 0.f;
#pragma unroll
  for (int j = 0; j < 8; ++j) {
    float a = m[j];
    float hfj[8];
    unpack8(hv[j], hfj);
#pragma unroll
    for (int e = 0; e < 8; ++e) pn[e] = fmaf(a, hfj[e], pn[e]);
  }
#pragma unroll
  for (int e = 0; e < 8; ++e) {
    pn[e] += __shfl_xor(pn[e], 16);
    pn[e] += __shfl_xor(pn[e], 32);
  }
  if (kg == 0) {
    const float* srow = self0 + (size_t)n * OUT_F + dg * 8;
    float* orow = out + (size_t)n * OUT_F + dg * 8;
    f32x4 o0, o1;
#pragma unroll
    for (int e = 0; e < 4; ++e)
      o0[e] = (srow[e] + pn[e] * scale) * 0.5f + out_bias[dg * 8 + e];
#pragma unroll
    for (int e = 0; e < 4; ++e)
      o1[e] = (srow[4 + e] + pn[4 + e] * scale) * 0.5f + out_bias[dg * 8 + 4 + e];
    *(f32x4*)orow = o0;
    *(f32x4*)(orow + 4) = o1;
  }
  if (kg == 1 && dg < LDIM)
    out[OUT_CENT + (size_t)n * LDIM + dg] = labels[(size_t)n * LDIM + dg];
  if (kg == 2 && dg < LDIM)
    out[OUT_LORI + (size_t)n * LDIM + dg] = labels_ori[(size_t)n * LDIM + dg];
}

// ---------------------------------------------------------------------------
extern "C" void kernel_launch(void* const* d_in, const int* in_sizes, int n_in,
                              void* d_out, int out_size, void* d_ws, size_t ws_size,
                              hipStream_t stream) {
  const float* feat       = (const float*)d_in[0];
  const float* labels     = (const float*)d_in[1];
  const float* labels_ori = (const float*)d_in[2];
  const float* label_rela = (const float*)d_in[3];
  const float* W_neigh    = (const float*)d_in[4];
  const float* b_neigh    = (const float*)d_in[5];
  const float* W_self     = (const float*)d_in[6];
  const float* b_self     = (const float*)d_in[7];
  const float* W_attn     = (const float*)d_in[8];
  // d_in[9] = b_attn (constant under softmax -> unused)
  const float* fW         = (const float*)d_in[10];
  const float* eps        = (const float*)d_in[11];
  const float* out_bias   = (const float*)d_in[12];
  const int*   nbr_idx    = (const int*)d_in[13];

  float* wsf = (float*)d_ws;
  float* out = (float*)d_out;

  float*  w_comb  = wsf + WS_WCOMB;
  ushort* Bn      = (ushort*)(wsf + WS_BN);
  ushort* Bsf     = (ushort*)(wsf + WS_BS);
  ushort* h_src   = (ushort*)(wsf + WS_HSRC);
  float*  self0   = wsf + WS_SELF0;
  float*  score_f = wsf + WS_SCORE;

  prep_kernel<<<384, 256, 0, stream>>>(W_attn, fW, W_neigh, W_self, w_comb, Bn, Bsf);
  fused_gemm<<<NB2_TOT, 128, 0, stream>>>(feat, Bn, Bsf, b_neigh, b_self,
                                          w_comb, h_src, self0, score_f);
  attn_kernel<<<(N_DST / 4), 256, 0, stream>>>(labels, labels_ori, label_rela, nbr_idx,
                                               h_src, self0, score_f, eps, out_bias, out);
}